// Round 8
// baseline (96.948 us; speedup 1.0000x reference)
//
#include <hip/hip_runtime.h>
#include <math.h>

#define RESG 128
#define CHG 28
#define NT 767
#define NLBKT 48   // length buckets (n_proc >> 4)

template <int PAT>
static __device__ __forceinline__ float swz(float x) {
    return __int_as_float(__builtin_amdgcn_ds_swizzle(__float_as_int(x), PAT));
}

// ---------- prep: sort rays by live-length, DESCENDING ----------
__global__ __launch_bounds__(1024) void prep_sort(
    const float* __restrict__ rays_d, const float* __restrict__ rays_o,
    int* __restrict__ perm, int B)
{
    __shared__ int cnt[64];
    __shared__ int off[64];
    __shared__ unsigned char keys[4096];
    const int tid = threadIdx.x;
    if (tid < 64) cnt[tid] = 0;
    __syncthreads();
    for (int r = tid; r < B; r += 1024) {
        const float ox = rays_o[r*3+0], oy = rays_o[r*3+1], oz = rays_o[r*3+2];
        const float dx = rays_d[r*3+0], dy = rays_d[r*3+1], dz = rays_d[r*3+2];
        float txp = (1.0f - ox)/dx, txn = (-1.0f - ox)/dx;
        float typ = (1.0f - oy)/dy, tyn = (-1.0f - oy)/dy;
        float tzp = (1.0f - oz)/dz, tzn = (-1.0f - oz)/dz;
        const float start = fmaxf(fmaxf(fminf(txp,txn), fminf(typ,tyn)), fminf(tzp,tzn));
        const float stop  = fminf(fminf(fmaxf(txp,txn), fmaxf(typ,tyn)), fmaxf(tzp,tzn));
        int n_proc = (int)((stop - start) * 127.0f) + 2;
        n_proc = n_proc < 0 ? 0 : (n_proc > NT ? NT : n_proc);
        int lvl = n_proc >> 4; if (lvl > NLBKT-1) lvl = NLBKT-1;
        const int k = (NLBKT-1) - lvl;            // descending length
        keys[r] = (unsigned char)k;
        atomicAdd(&cnt[k], 1);
    }
    __syncthreads();
    if (tid < 64) {
        int v = cnt[tid];
        int incl = v;
        #pragma unroll
        for (int o2 = 1; o2 < 64; o2 <<= 1) {
            const int n = __shfl_up(incl, o2, 64);
            if ((tid & 63) >= o2) incl += n;
        }
        off[tid] = incl - v;
    }
    __syncthreads();
    for (int r = tid; r < B; r += 1024) {
        const int slot = atomicAdd(&off[keys[r]], 1);
        perm[slot] = r;
    }
}

// ---------- main: ONE RAY PER WAVE, 64-thread blocks, no LDS, no barriers ----------
__global__ __launch_bounds__(64) void nerf_grid_kernel(
    const float* __restrict__ rays_d,
    const float* __restrict__ rays_o,
    const float* __restrict__ grid,     // [128^3][28] f32, 112B rows
    const int*   __restrict__ perm,
    float* __restrict__ out_rgb,
    float* __restrict__ out_alpha,
    float* __restrict__ out_depth)
{
    const int ray  = perm[blockIdx.x];
    const int lane = threadIdx.x & 63;

    const float EPSC   = 1e-10f;
    const float INV127 = 1.0f / 127.0f;

    // ---- per-ray setup ----
    const float ox = rays_o[ray*3+0], oy = rays_o[ray*3+1], oz = rays_o[ray*3+2];
    const float dx = rays_d[ray*3+0], dy = rays_d[ray*3+1], dz = rays_d[ray*3+2];
    const float dnorm = sqrtf(dx*dx + dy*dy + dz*dz);

    float txp = (1.0f - ox)/dx, txn = (-1.0f - ox)/dx;
    float typ = (1.0f - oy)/dy, tyn = (-1.0f - oy)/dy;
    float tzp = (1.0f - oz)/dz, tzn = (-1.0f - oz)/dz;
    const float start = fmaxf(fmaxf(fminf(txp,txn), fminf(typ,tyn)), fminf(tzp,tzn));
    const float stop  = fminf(fminf(fmaxf(txp,txn), fmaxf(typ,tyn)), fmaxf(tzp,tzn));

    int n_proc = (int)((stop - start) * 127.0f) + 2;
    n_proc = n_proc < 0 ? 0 : (n_proc > NT ? NT : n_proc);

    // SH deg-2 basis (all lanes)
    const float inv = 1.0f/dnorm;
    const float nx = dx*inv, ny = dy*inv, nz = dz*inv;
    float sh[9];
    {
        const float C0 = 0.28209479177387814f;
        const float C1 = 0.4886025119029199f;
        const float C20 = 1.0925484305920792f, C21 = -1.0925484305920792f;
        const float C22 = 0.31539156525252005f;
        const float C23 = -1.0925484305920792f, C24 = 0.5462742152960396f;
        sh[0] = C0;   sh[1] = -C1*ny; sh[2] = C1*nz; sh[3] = -C1*nx;
        sh[4] = C20*nx*ny; sh[5] = C21*ny*nz;
        sh[6] = C22*(2.0f*nz*nz - nx*nx - ny*ny);
        sh[7] = C23*nx*nz; sh[8] = C24*(nx*nx - ny*ny);
    }

    // ---- per-lane channel-slice coefficients ----
    // lane = samp(3b) | j(3b): j = chunk index (channels 4j..4j+3); j==7 dup chunk6, zero coefs
    const int samp = lane >> 3;
    const int j    = lane & 7;
    float cR[4], cG[4], cB[4];
    #pragma unroll
    for (int m = 0; m < 4; ++m) {
        const int ch = 4*j + m;
        cR[m] = (ch < 9)              ? sh[ch]    : 0.0f;
        cG[m] = (ch >= 9 && ch < 18)  ? sh[ch-9]  : 0.0f;
        cB[m] = (ch >= 18 && ch < 27) ? sh[ch-18] : 0.0f;
    }
    const float cS3 = (j == 6) ? 1.0f : 0.0f;   // sigma = channel 27
    const int chunk_off = (j < 7 ? j : 6) << 4; // bytes
    const char* gridc = (const char*)grid;

    const size_t rayNT = (size_t)ray * NT;

    // ---- running state ----
    float T = 1.0f;                                   // transmittance carry
    float accA = 0.0f, accR = 0.0f, accG = 0.0f, accB = 0.0f, accD = 0.0f;

    // ---- main loop: wave handles 8 consecutive samples per iteration ----
    for (int base = 0; base < n_proc; base += 8) {
        const int s = base + samp;
        const float t0 = fminf(start + (float)(s+1)*INV127, stop);
        const float t1 = fminf(start + (float)(s+2)*INV127, stop);
        const float dist = (t1 - t0) * dnorm;
        const bool live = (s < n_proc) && (dist > 0.0f);

        // clamped continuous coords (guards fp slop at faces)
        const float gx = fminf(fmaxf((ox + t0*dx + 1.0f)*63.5f, 0.0f), 127.0f);
        const float gy = fminf(fmaxf((oy + t0*dy + 1.0f)*63.5f, 0.0f), 127.0f);
        const float gz = fminf(fmaxf((oz + t0*dz + 1.0f)*63.5f, 0.0f), 127.0f);
        const float fx0 = floorf(gx), fy0 = floorf(gy), fz0 = floorf(gz);
        const float fx = gx - fx0, fy = gy - fy0, fz = gz - fz0;
        const int ix = (int)fx0, iy = (int)fy0, iz = (int)fz0;

        const int Bv = ((iz*RESG + iy)*RESG + ix)*112 + chunk_off;
        const int offx = (ix < RESG-1) ? 112 : 0;     // clamp == zero offset (weight 0 there)
        const int offy = (iy < RESG-1) ? 112*RESG : 0;
        const int offz = (iz < RESG-1) ? 112*RESG*RESG : 0;
        int offs[8];
        offs[0] = 0;           offs[1] = offx;
        offs[2] = offy;        offs[3] = offx + offy;
        offs[4] = offz;        offs[5] = offz + offx;
        offs[6] = offz + offy; offs[7] = offz + offx + offy;

        const float liveF = live ? 1.0f : 0.0f;
        const float wx1 = fx, wx0 = 1.0f - fx;
        const float wy1 = fy, wy0 = 1.0f - fy;
        const float wz1 = fz*liveF, wz0 = (1.0f - fz)*liveF;
        const float w00 = wx0*wy0, w10 = wx1*wy0, w01 = wx0*wy1, w11 = wx1*wy1;
        float wc[8];
        wc[0] = w00*wz0; wc[1] = w10*wz0; wc[2] = w01*wz0; wc[3] = w11*wz0;
        wc[4] = w00*wz1; wc[5] = w10*wz1; wc[6] = w01*wz1; wc[7] = w11*wz1;

        // 8 corner loads: j-lanes 0..6 cover each row contiguously (112B)
        float av0 = 0.0f, av1 = 0.0f, av2 = 0.0f, av3 = 0.0f;
        #pragma unroll
        for (int i = 0; i < 8; ++i) {
            const float4 v = *(const float4*)(gridc + (size_t)(unsigned)(Bv + offs[i]));
            av0 = fmaf(wc[i], v.x, av0);
            av1 = fmaf(wc[i], v.y, av1);
            av2 = fmaf(wc[i], v.z, av2);
            av3 = fmaf(wc[i], v.w, av3);
        }

        // per-lane channel-slice dots
        float rr = av0*cR[0] + av1*cR[1] + av2*cR[2] + av3*cR[3];
        float gg = av0*cG[0] + av1*cG[1] + av2*cG[2] + av3*cG[3];
        float bb = av0*cB[0] + av1*cB[1] + av2*cB[2] + av3*cB[3];
        float sg = av3*cS3;

        // xor-butterfly over the 8 chunk lanes -> ALL lanes of a group hold the full sums
        rr += swz<0x041F>(rr); gg += swz<0x041F>(gg); bb += swz<0x041F>(bb); sg += swz<0x041F>(sg);
        rr += swz<0x081F>(rr); gg += swz<0x081F>(gg); bb += swz<0x081F>(bb); sg += swz<0x081F>(sg);
        rr += swz<0x101F>(rr); gg += swz<0x101F>(gg); bb += swz<0x101F>(bb); sg += swz<0x101F>(sg);

        // alpha & sigmoid on all lanes (group-uniform, no divergence)
        const float a = live ? (1.0f - expf(-fmaxf(sg, 0.0f)*dist)) : 0.0f;
        const float q = (s < n_proc) ? (1.0f - a + EPSC) : 1.0f;
        const float r1 = 1.0f/(1.0f + expf(-rr));
        const float g1 = 1.0f/(1.0f + expf(-gg));
        const float b1 = 1.0f/(1.0f + expf(-bb));

        // group-stride inclusive product scan over the 8 sample-groups
        float incl = q;
        { const float n = __shfl_up(incl,  8, 64); if (lane >=  8) incl *= n; }
        { const float n = __shfl_up(incl, 16, 64); if (lane >= 16) incl *= n; }
        { const float n = __shfl_up(incl, 32, 64); if (lane >= 32) incl *= n; }
        float excl = __shfl_up(incl, 8, 64);
        if (lane < 8) excl = 1.0f;

        const float abs_l = a * T * excl;
        accA += abs_l;
        accR += abs_l * r1;
        accG += abs_l * g1;
        accB += abs_l * b1;
        accD += abs_l * t0;

        // coalesced alpha store: collect group alphas into lanes 0..7
        const float a_out = __shfl(a, (lane & 7) * 8, 64);
        if (lane < 8 && base + lane < n_proc)
            out_alpha[rayNT + base + lane] = a_out;

        // advance carry
        T *= __shfl(incl, 56, 64);
    }

    // zero-fill dead alpha range
    for (int s2 = n_proc + lane; s2 < NT; s2 += 64)
        out_alpha[rayNT + s2] = 0.0f;

    // reduce across the 8 groups (values group-uniform)
    accA += __shfl_down(accA,  8, 64);
    accR += __shfl_down(accR,  8, 64);
    accG += __shfl_down(accG,  8, 64);
    accB += __shfl_down(accB,  8, 64);
    accD += __shfl_down(accD,  8, 64);
    accA += __shfl_down(accA, 16, 64);
    accR += __shfl_down(accR, 16, 64);
    accG += __shfl_down(accG, 16, 64);
    accB += __shfl_down(accB, 16, 64);
    accD += __shfl_down(accD, 16, 64);
    accA += __shfl_down(accA, 32, 64);
    accR += __shfl_down(accR, 32, 64);
    accG += __shfl_down(accG, 32, 64);
    accB += __shfl_down(accB, 32, 64);
    accD += __shfl_down(accD, 32, 64);

    if (lane == 0) {
        const float bg = 1.0f - accA;
        out_rgb[ray*3+0] = accR + bg;
        out_rgb[ray*3+1] = accG + bg;
        out_rgb[ray*3+2] = accB + bg;
        out_depth[ray] = accD;
    }
}

extern "C" void kernel_launch(void* const* d_in, const int* in_sizes, int n_in,
                              void* d_out, int out_size, void* d_ws, size_t ws_size,
                              hipStream_t stream) {
    const float* rays_d = (const float*)d_in[0];
    const float* rays_o = (const float*)d_in[1];
    const float* grid   = (const float*)d_in[2];
    const int B = in_sizes[0] / 3;   // 4096

    float* out       = (float*)d_out;
    float* out_rgb   = out;
    float* out_alpha = out + (size_t)B*3;
    float* out_depth = out + (size_t)B*3 + (size_t)B*NT;

    int* perm = (int*)d_ws;

    prep_sort<<<1, 1024, 0, stream>>>(rays_d, rays_o, perm, B);
    nerf_grid_kernel<<<B, 64, 0, stream>>>(rays_d, rays_o, grid, perm,
                                           out_rgb, out_alpha, out_depth);
}

// Round 9
// 87.906 us; speedup vs baseline: 1.1029x; 1.1029x over previous
//
#include <hip/hip_runtime.h>
#include <math.h>

#define RESG 128
#define CHG 28
#define NT 767
#define NLBKT 48   // length buckets (n_proc >> 4)

template <int PAT>
static __device__ __forceinline__ float swz(float x) {
    return __int_as_float(__builtin_amdgcn_ds_swizzle(__float_as_int(x), PAT));
}
static __device__ __forceinline__ unsigned short f2bf(float x) {
    unsigned u = __float_as_uint(x);
    return (unsigned short)((u + 0x7FFFu + ((u >> 16) & 1u)) >> 16);
}
static __device__ __forceinline__ float bf2f(unsigned short h) {
    return __uint_as_float(((unsigned)h) << 16);
}

// ---------- prep: sort rays by live-length, DESCENDING ----------
__global__ __launch_bounds__(1024) void prep_sort(
    const float* __restrict__ rays_d, const float* __restrict__ rays_o,
    int* __restrict__ perm, int B)
{
    __shared__ int cnt[64];
    __shared__ int off[64];
    __shared__ unsigned char keys[4096];
    const int tid = threadIdx.x;
    if (tid < 64) cnt[tid] = 0;
    __syncthreads();
    for (int r = tid; r < B; r += 1024) {
        const float ox = rays_o[r*3+0], oy = rays_o[r*3+1], oz = rays_o[r*3+2];
        const float dx = rays_d[r*3+0], dy = rays_d[r*3+1], dz = rays_d[r*3+2];
        float txp = (1.0f - ox)/dx, txn = (-1.0f - ox)/dx;
        float typ = (1.0f - oy)/dy, tyn = (-1.0f - oy)/dy;
        float tzp = (1.0f - oz)/dz, tzn = (-1.0f - oz)/dz;
        const float start = fmaxf(fmaxf(fminf(txp,txn), fminf(typ,tyn)), fminf(tzp,tzn));
        const float stop  = fminf(fminf(fmaxf(txp,txn), fmaxf(typ,tyn)), fmaxf(tzp,tzn));
        int n_proc = (int)((stop - start) * 127.0f) + 2;
        n_proc = n_proc < 0 ? 0 : (n_proc > NT ? NT : n_proc);
        int lvl = n_proc >> 4; if (lvl > NLBKT-1) lvl = NLBKT-1;
        const int k = (NLBKT-1) - lvl;            // descending length
        keys[r] = (unsigned char)k;
        atomicAdd(&cnt[k], 1);
    }
    __syncthreads();
    if (tid < 64) {
        int v = cnt[tid];
        int incl = v;
        #pragma unroll
        for (int o2 = 1; o2 < 64; o2 <<= 1) {
            const int n = __shfl_up(incl, o2, 64);
            if ((tid & 63) >= o2) incl += n;
        }
        off[tid] = incl - v;
    }
    __syncthreads();
    for (int r = tid; r < B; r += 1024) {
        const int slot = atomicAdd(&off[keys[r]], 1);
        perm[slot] = r;
    }
}

// ---------- main: 128 threads (2 waves) per ray ----------
__global__ __launch_bounds__(128) void nerf_grid_kernel(
    const float* __restrict__ rays_d,
    const float* __restrict__ rays_o,
    const float* __restrict__ grid,     // [128^3][28] f32, 112B rows
    const int*   __restrict__ perm,
    float* __restrict__ out_rgb,
    float* __restrict__ out_alpha,
    float* __restrict__ out_depth)
{
    const int ray  = perm[blockIdx.x];
    const int tid  = threadIdx.x;
    const int lane = tid & 63;
    const int wave = tid >> 6;

    const float EPSC   = 1e-10f;
    const float INV127 = 1.0f / 127.0f;

    __shared__ float        a_lds[NT + 1];   // 3072 B
    __shared__ unsigned int rg_lds[NT + 1];  // 3072 B  (bf16 r | bf16 g)
    __shared__ unsigned short b_lds[NT + 1]; // 1536 B  (bf16 b)
    __shared__ float wprod[2];
    __shared__ float red[2][5];

    // ---- per-ray setup ----
    const float ox = rays_o[ray*3+0], oy = rays_o[ray*3+1], oz = rays_o[ray*3+2];
    const float dx = rays_d[ray*3+0], dy = rays_d[ray*3+1], dz = rays_d[ray*3+2];
    const float dnorm = sqrtf(dx*dx + dy*dy + dz*dz);

    float txp = (1.0f - ox)/dx, txn = (-1.0f - ox)/dx;
    float typ = (1.0f - oy)/dy, tyn = (-1.0f - oy)/dy;
    float tzp = (1.0f - oz)/dz, tzn = (-1.0f - oz)/dz;
    const float start = fmaxf(fmaxf(fminf(txp,txn), fminf(typ,tyn)), fminf(tzp,tzn));
    const float stop  = fminf(fminf(fmaxf(txp,txn), fmaxf(typ,tyn)), fmaxf(tzp,tzn));

    int n_proc = (int)((stop - start) * 127.0f) + 2;
    n_proc = n_proc < 0 ? 0 : (n_proc > NT ? NT : n_proc);

    // SH deg-2 basis (registers, all lanes)
    const float inv = 1.0f/dnorm;
    const float nx = dx*inv, ny = dy*inv, nz = dz*inv;
    float sh0, sh1, sh2, sh3, sh4, sh5, sh6, sh7, sh8;
    {
        const float C0 = 0.28209479177387814f;
        const float C1 = 0.4886025119029199f;
        const float C20 = 1.0925484305920792f, C21 = -1.0925484305920792f;
        const float C22 = 0.31539156525252005f;
        const float C23 = -1.0925484305920792f, C24 = 0.5462742152960396f;
        sh0 = C0;   sh1 = -C1*ny; sh2 = C1*nz; sh3 = -C1*nx;
        sh4 = C20*nx*ny; sh5 = C21*ny*nz;
        sh6 = C22*(2.0f*nz*nz - nx*nx - ny*ny);
        sh7 = C23*nx*nz; sh8 = C24*(nx*nx - ny*ny);
    }

    // ---- phase 1: lane-per-corner gather; each wave does 8 samples/iter ----
    const int samp   = lane >> 3;     // 0..7
    const int corner = lane & 7;      // bit0=x, bit1=y, bit2=z
    const int cdx = corner & 1, cdy = (corner >> 1) & 1, cdz = corner >> 2;
    const char* gridc = (const char*)grid;

    for (int base = wave*8; base < n_proc; base += 16) {
        const int s = base + samp;
        const float t0 = fminf(fmaf((float)(s+1), INV127, start), stop);
        const float t1 = fminf(fmaf((float)(s+2), INV127, start), stop);
        const float dist = (t1 - t0) * dnorm;
        const bool live = (s < n_proc) && (dist > 0.0f);

        // clamped continuous coords (guards fp slop at faces; semantics ~= reference)
        const float gx = fminf(fmaxf((ox + t0*dx + 1.0f)*63.5f, 0.0f), 127.0f);
        const float gy = fminf(fmaxf((oy + t0*dy + 1.0f)*63.5f, 0.0f), 127.0f);
        const float gz = fminf(fmaxf((oz + t0*dz + 1.0f)*63.5f, 0.0f), 127.0f);
        const float fx0 = floorf(gx), fy0 = floorf(gy), fz0 = floorf(gz);
        const float fx = gx - fx0, fy = gy - fy0, fz = gz - fz0;
        const int ix = (int)fx0, iy = (int)fy0, iz = (int)fz0;

        const int Bv   = ((iz*RESG + iy)*RESG + ix)*112;
        const int offx = cdx ? ((ix < RESG-1) ? 112 : 0) : 0;
        const int offy = cdy ? ((iy < RESG-1) ? 112*RESG : 0) : 0;
        const int offz = cdz ? ((iz < RESG-1) ? 112*RESG*RESG : 0) : 0;
        const unsigned rowB = (unsigned)(Bv + offx + offy + offz);

        const float liveF = live ? 1.0f : 0.0f;
        const float w = (cdx ? fx : 1.0f-fx) *
                        (cdy ? fy : 1.0f-fy) *
                        ((cdz ? fz : 1.0f-fz) * liveF);

        const float4* row = (const float4*)(gridc + (size_t)rowB);
        const float4 v0 = row[0], v1 = row[1], v2 = row[2], v3 = row[3];
        const float4 v4 = row[4], v5 = row[5], v6 = row[6];
        float rr = w*(v0.x*sh0 + v0.y*sh1 + v0.z*sh2 + v0.w*sh3 +
                      v1.x*sh4 + v1.y*sh5 + v1.z*sh6 + v1.w*sh7 + v2.x*sh8);
        float gg = w*(v2.y*sh0 + v2.z*sh1 + v2.w*sh2 + v3.x*sh3 +
                      v3.y*sh4 + v3.z*sh5 + v3.w*sh6 + v4.x*sh7 + v4.y*sh8);
        float bb = w*(v4.z*sh0 + v4.w*sh1 + v5.x*sh2 + v5.y*sh3 +
                      v5.z*sh4 + v5.w*sh5 + v6.x*sh6 + v6.y*sh7 + v6.z*sh8);
        float sg = w*v6.w;

        // reduce over the 8 corner lanes (xor 1,2,4)
        rr += swz<0x041F>(rr); gg += swz<0x041F>(gg); bb += swz<0x041F>(bb); sg += swz<0x041F>(sg);
        rr += swz<0x081F>(rr); gg += swz<0x081F>(gg); bb += swz<0x081F>(bb); sg += swz<0x081F>(sg);
        rr += swz<0x101F>(rr); gg += swz<0x101F>(gg); bb += swz<0x101F>(bb); sg += swz<0x101F>(sg);

        if (corner == 0 && s < n_proc) {
            a_lds[s] = live ? (1.0f - __expf(-fmaxf(sg, 0.0f)*dist)) : 0.0f;
            const float r1 = __builtin_amdgcn_rcpf(1.0f + __expf(-rr));
            const float g1 = __builtin_amdgcn_rcpf(1.0f + __expf(-gg));
            const float b1 = __builtin_amdgcn_rcpf(1.0f + __expf(-bb));
            rg_lds[s] = ((unsigned)f2bf(r1) << 16) | (unsigned)f2bf(g1);
            b_lds[s]  = f2bf(b1);
        }
    }
    __syncthreads();

    // coalesced alpha output (zeros for dead range)
    for (int s = tid; s < NT; s += 128)
        out_alpha[(size_t)ray*NT + s] = (s < n_proc) ? a_lds[s] : 0.0f;

    // ---- phase 2: per-thread 6 consecutive samples, product from LDS ----
    const int s0i = tid * 6;
    float prod = 1.0f;
    #pragma unroll
    for (int k = 0; k < 6; ++k) {
        const int s = s0i + k;
        if (s < NT) {
            const float a = (s < n_proc) ? a_lds[s] : 0.0f;
            prod *= (1.0f - a + EPSC);
        }
    }

    // wave-wide exclusive product scan
    float incl = prod;
    #pragma unroll
    for (int off2 = 1; off2 < 64; off2 <<= 1) {
        const float n = __shfl_up(incl, off2, 64);
        if (lane >= off2) incl *= n;
    }
    float excl = __shfl_up(incl, 1, 64);
    if (lane == 0) excl = 1.0f;

    if (lane == 63) wprod[wave] = incl;
    __syncthreads();
    const float wpre = (wave == 1) ? wprod[0] : 1.0f;

    // ---- phase 3: weighted accumulation (reload from LDS) ----
    float cum = wpre * excl;
    float accA = 0.0f, accR = 0.0f, accG = 0.0f, accB = 0.0f, accD = 0.0f;
    #pragma unroll
    for (int k = 0; k < 6; ++k) {
        const int s = s0i + k;
        if (s < NT) {
            const float a = (s < n_proc) ? a_lds[s] : 0.0f;
            const float abs_l = a * cum;
            if (s < n_proc) {
                const unsigned rg = rg_lds[s];
                const float tt = fminf(fmaf((float)(s+1), INV127, start), stop);
                accA += abs_l;
                accR += abs_l * bf2f((unsigned short)(rg >> 16));
                accG += abs_l * bf2f((unsigned short)(rg & 0xFFFFu));
                accB += abs_l * bf2f(b_lds[s]);
                accD += abs_l * tt;
            }
            cum *= (1.0f - a + EPSC);
        }
    }

    #pragma unroll
    for (int off2 = 32; off2 > 0; off2 >>= 1) {
        accA += __shfl_down(accA, off2, 64);
        accR += __shfl_down(accR, off2, 64);
        accG += __shfl_down(accG, off2, 64);
        accB += __shfl_down(accB, off2, 64);
        accD += __shfl_down(accD, off2, 64);
    }
    if (lane == 0) {
        red[wave][0] = accA; red[wave][1] = accR; red[wave][2] = accG;
        red[wave][3] = accB; red[wave][4] = accD;
    }
    __syncthreads();
    if (tid == 0) {
        const float A  = red[0][0] + red[1][0];
        const float R  = red[0][1] + red[1][1];
        const float G  = red[0][2] + red[1][2];
        const float Bv = red[0][3] + red[1][3];
        const float D  = red[0][4] + red[1][4];
        const float bg = 1.0f - A;
        out_rgb[ray*3+0] = R  + bg;
        out_rgb[ray*3+1] = G  + bg;
        out_rgb[ray*3+2] = Bv + bg;
        out_depth[ray] = D;
    }
}

extern "C" void kernel_launch(void* const* d_in, const int* in_sizes, int n_in,
                              void* d_out, int out_size, void* d_ws, size_t ws_size,
                              hipStream_t stream) {
    const float* rays_d = (const float*)d_in[0];
    const float* rays_o = (const float*)d_in[1];
    const float* grid   = (const float*)d_in[2];
    const int B = in_sizes[0] / 3;   // 4096

    float* out       = (float*)d_out;
    float* out_rgb   = out;
    float* out_alpha = out + (size_t)B*3;
    float* out_depth = out + (size_t)B*3 + (size_t)B*NT;

    int* perm = (int*)d_ws;

    prep_sort<<<1, 1024, 0, stream>>>(rays_d, rays_o, perm, B);
    nerf_grid_kernel<<<B, 128, 0, stream>>>(rays_d, rays_o, grid, perm,
                                            out_rgb, out_alpha, out_depth);
}

// Round 10
// 85.307 us; speedup vs baseline: 1.1365x; 1.0305x over previous
//
#include <hip/hip_runtime.h>
#include <math.h>

#define RESG 128
#define CHG 28
#define NT 767
#define NKEY 512   // 64 entry cells x 8 direction octants

template <int PAT>
static __device__ __forceinline__ float swz(float x) {
    return __int_as_float(__builtin_amdgcn_ds_swizzle(__float_as_int(x), PAT));
}

// ---------- prep: chord-locality sort + XCD-aligned placement ----------
__global__ __launch_bounds__(1024) void prep_sort(
    const float* __restrict__ rays_d, const float* __restrict__ rays_o,
    int* __restrict__ perm, int B)
{
    __shared__ int cnt[NKEY];
    __shared__ int off[NKEY];
    __shared__ unsigned short keys[4096];
    __shared__ int sorted_l[4096];          // 16 KB
    const int tid = threadIdx.x;
    for (int i = tid; i < NKEY; i += 1024) cnt[i] = 0;
    __syncthreads();
    for (int r = tid; r < B; r += 1024) {
        const float ox = rays_o[r*3+0], oy = rays_o[r*3+1], oz = rays_o[r*3+2];
        const float dx = rays_d[r*3+0], dy = rays_d[r*3+1], dz = rays_d[r*3+2];
        float txp = (1.0f - ox)/dx, txn = (-1.0f - ox)/dx;
        float typ = (1.0f - oy)/dy, tyn = (-1.0f - oy)/dy;
        float tzp = (1.0f - oz)/dz, tzn = (-1.0f - oz)/dz;
        const float start = fmaxf(fmaxf(fminf(txp,txn), fminf(typ,tyn)), fminf(tzp,tzn));
        // entry point in [-1,1]^3 -> 4x4x4 cell
        const float pex = ox + start*dx, pey = oy + start*dy, pez = oz + start*dz;
        int ex = (int)fminf(fmaxf((pex + 1.0f)*2.0f, 0.0f), 3.0f);
        int ey = (int)fminf(fmaxf((pey + 1.0f)*2.0f, 0.0f), 3.0f);
        int ez = (int)fminf(fmaxf((pez + 1.0f)*2.0f, 0.0f), 3.0f);
        const int oct = ((dx < 0.f) ? 1 : 0) | ((dy < 0.f) ? 2 : 0) | ((dz < 0.f) ? 4 : 0);
        const int k = ((ex << 7) | (ey << 5) | (ez << 3) | oct) & (NKEY - 1);
        keys[r] = (unsigned short)k;
        atomicAdd(&cnt[k], 1);
    }
    __syncthreads();
    // exclusive prefix over NKEY counters (Hillis-Steele in LDS)
    if (tid < NKEY) off[tid] = cnt[tid];
    __syncthreads();
    for (int d = 1; d < NKEY; d <<= 1) {
        int v = 0;
        if (tid < NKEY && tid >= d) v = off[tid - d];
        __syncthreads();
        if (tid < NKEY && tid >= d) off[tid] += v;
        __syncthreads();
    }
    if (tid < NKEY) off[tid] -= cnt[tid];   // exclusive
    __syncthreads();
    for (int r = tid; r < B; r += 1024) {
        const int slot = atomicAdd(&off[keys[r]], 1);
        sorted_l[slot] = r;
    }
    __syncthreads();
    // XCD-aligned placement: sorted-consecutive -> same blockIdx residue mod 8
    const int cpx = B >> 3;                 // B assumed divisible by 8
    for (int i = tid; i < B; i += 1024) {
        const int src = (B & 7) ? i : ((i & 7) * cpx + (i >> 3));
        perm[i] = sorted_l[src];
    }
}

// ---------- main (R5 structure) ----------
__global__ __launch_bounds__(256) void nerf_grid_kernel(
    const float* __restrict__ rays_d,
    const float* __restrict__ rays_o,
    const float* __restrict__ grid,     // [128^3][28] f32
    const int*   __restrict__ perm,
    float* __restrict__ out_rgb,
    float* __restrict__ out_alpha,
    float* __restrict__ out_depth)
{
    const int ray  = perm[blockIdx.x];
    const int tid  = threadIdx.x;
    const int lane = tid & 63;
    const int wave = tid >> 6;

    const float EPSC   = 1e-10f;
    const float INV127 = 1.0f / 127.0f;

    __shared__ float a_lds[NT + 1];
    __shared__ float r_lds[NT + 1];
    __shared__ float g_lds[NT + 1];
    __shared__ float b_lds[NT + 1];
    __shared__ float wprod[4];
    __shared__ float red[4][5];

    // ---- per-ray setup ----
    const float ox = rays_o[ray*3+0], oy = rays_o[ray*3+1], oz = rays_o[ray*3+2];
    const float dx = rays_d[ray*3+0], dy = rays_d[ray*3+1], dz = rays_d[ray*3+2];
    const float dnorm = sqrtf(dx*dx + dy*dy + dz*dz);

    float txp = (1.0f - ox)/dx, txn = (-1.0f - ox)/dx;
    float typ = (1.0f - oy)/dy, tyn = (-1.0f - oy)/dy;
    float tzp = (1.0f - oz)/dz, tzn = (-1.0f - oz)/dz;
    const float start = fmaxf(fmaxf(fminf(txp,txn), fminf(typ,tyn)), fminf(tzp,tzn));
    const float stop  = fminf(fminf(fmaxf(txp,txn), fmaxf(typ,tyn)), fmaxf(tzp,tzn));

    int n_proc = (int)((stop - start) * 127.0f) + 2;
    n_proc = n_proc < 0 ? 0 : (n_proc > NT ? NT : n_proc);

    // SH deg-2 basis
    const float inv = 1.0f/dnorm;
    const float nx = dx*inv, ny = dy*inv, nz = dz*inv;
    float sh0, sh1, sh2, sh3, sh4, sh5, sh6, sh7, sh8;
    {
        const float C0 = 0.28209479177387814f;
        const float C1 = 0.4886025119029199f;
        const float C20 = 1.0925484305920792f, C21 = -1.0925484305920792f;
        const float C22 = 0.31539156525252005f;
        const float C23 = -1.0925484305920792f, C24 = 0.5462742152960396f;
        sh0 = C0;   sh1 = -C1*ny; sh2 = C1*nz; sh3 = -C1*nx;
        sh4 = C20*nx*ny; sh5 = C21*ny*nz;
        sh6 = C22*(2.0f*nz*nz - nx*nx - ny*ny);
        sh7 = C23*nx*nz; sh8 = C24*(nx*nx - ny*ny);
    }

    // ---- phase 1: lane-per-corner gather; wave handles 8 consecutive samples ----
    const int samp   = lane >> 3;     // 0..7
    const int corner = lane & 7;      // bit0=dx, bit1=dy, bit2=dz
    const int cdx = corner & 1, cdy = (corner >> 1) & 1, cdz = corner >> 2;

    for (int base = wave*8; base < n_proc; base += 32) {
        const int s = base + samp;
        float rr = 0.0f, gg = 0.0f, bb = 0.0f, sg = 0.0f;
        float t0 = 0.0f, dist = 0.0f;
        bool live = false;
        if (s < n_proc) {
            t0 = fminf(fmaf((float)(s+1), INV127, start), stop);
            const float t1 = fminf(fmaf((float)(s+2), INV127, start), stop);
            dist = (t1 - t0) * dnorm;
            live = dist > 0.0f;
        }
        if (live) {
            const float gx = (ox + t0*dx + 1.0f)*63.5f;
            const float gy = (oy + t0*dy + 1.0f)*63.5f;
            const float gz = (oz + t0*dz + 1.0f)*63.5f;
            const float fx0 = floorf(gx), fy0 = floorf(gy), fz0 = floorf(gz);
            const float fx = gx - fx0, fy = gy - fy0, fz = gz - fz0;
            const int xi = (int)fx0 + cdx;
            const int yi = (int)fy0 + cdy;
            const int zi = (int)fz0 + cdz;
            const bool valid = ((unsigned)xi < (unsigned)RESG) &
                               ((unsigned)yi < (unsigned)RESG) &
                               ((unsigned)zi < (unsigned)RESG);
            const float w = (cdx ? fx : 1.0f-fx) *
                            (cdy ? fy : 1.0f-fy) *
                            (cdz ? fz : 1.0f-fz);
            if (valid && w != 0.0f) {
                const float4* row = (const float4*)(grid + (size_t)(((zi*RESG) + yi)*RESG + xi)*CHG);
                const float4 v0 = row[0], v1 = row[1], v2 = row[2], v3 = row[3];
                const float4 v4 = row[4], v5 = row[5], v6 = row[6];
                rr = w*(v0.x*sh0 + v0.y*sh1 + v0.z*sh2 + v0.w*sh3 +
                        v1.x*sh4 + v1.y*sh5 + v1.z*sh6 + v1.w*sh7 + v2.x*sh8);
                gg = w*(v2.y*sh0 + v2.z*sh1 + v2.w*sh2 + v3.x*sh3 +
                        v3.y*sh4 + v3.z*sh5 + v3.w*sh6 + v4.x*sh7 + v4.y*sh8);
                bb = w*(v4.z*sh0 + v4.w*sh1 + v5.x*sh2 + v5.y*sh3 +
                        v5.z*sh4 + v5.w*sh5 + v6.x*sh6 + v6.y*sh7 + v6.z*sh8);
                sg = w*v6.w;
            }
        }
        rr += swz<0x041F>(rr); gg += swz<0x041F>(gg); bb += swz<0x041F>(bb); sg += swz<0x041F>(sg);
        rr += swz<0x081F>(rr); gg += swz<0x081F>(gg); bb += swz<0x081F>(bb); sg += swz<0x081F>(sg);
        rr += swz<0x101F>(rr); gg += swz<0x101F>(gg); bb += swz<0x101F>(bb); sg += swz<0x101F>(sg);

        if (corner == 0 && s < n_proc) {
            a_lds[s] = live ? (1.0f - __expf(-fmaxf(sg, 0.0f)*dist)) : 0.0f;
            r_lds[s] = __builtin_amdgcn_rcpf(1.0f + __expf(-rr));
            g_lds[s] = __builtin_amdgcn_rcpf(1.0f + __expf(-gg));
            b_lds[s] = __builtin_amdgcn_rcpf(1.0f + __expf(-bb));
        }
    }
    __syncthreads();

    // coalesced alpha output (zeros for dead range)
    for (int s = tid; s < NT; s += 256)
        out_alpha[(size_t)ray*NT + s] = (s < n_proc) ? a_lds[s] : 0.0f;

    // ---- phase 2: per-thread 3 consecutive samples ----
    float a_r[3], q_r[3], t_r[3], rr_r[3], gg_r[3], bb_r[3];
    #pragma unroll
    for (int k = 0; k < 3; ++k) {
        const int s = tid*3 + k;
        float a = 0.0f, rr = 0.0f, gg = 0.0f, bb = 0.0f, tt = 0.0f;
        if (s < NT) {
            tt = fminf(fmaf((float)(s+1), INV127, start), stop);
            if (s < n_proc) {
                a = a_lds[s];
                rr = r_lds[s]; gg = g_lds[s]; bb = b_lds[s];
            }
        }
        a_r[k] = a; q_r[k] = (s < NT) ? (1.0f - a + EPSC) : 1.0f;
        t_r[k] = tt; rr_r[k] = rr; gg_r[k] = gg; bb_r[k] = bb;
    }

    // ---- block-wide exclusive product scan ----
    const float P = q_r[0]*q_r[1]*q_r[2];
    float incl = P;
    #pragma unroll
    for (int off2 = 1; off2 < 64; off2 <<= 1) {
        const float n = __shfl_up(incl, off2, 64);
        if (lane >= off2) incl *= n;
    }
    float excl = __shfl_up(incl, 1, 64);
    if (lane == 0) excl = 1.0f;

    if (lane == 63) wprod[wave] = incl;
    __syncthreads();
    float wpre = 1.0f;
    for (int w2 = 0; w2 < 4; ++w2) if (w2 < wave) wpre *= wprod[w2];

    // ---- phase 3: weighted accumulation ----
    float cum = wpre * excl;
    float accA = 0.0f, accR = 0.0f, accG = 0.0f, accB = 0.0f, accD = 0.0f;
    #pragma unroll
    for (int k = 0; k < 3; ++k) {
        const float abs_l = a_r[k] * cum;
        accA += abs_l;
        accR += abs_l * rr_r[k];
        accG += abs_l * gg_r[k];
        accB += abs_l * bb_r[k];
        accD += abs_l * t_r[k];
        cum *= q_r[k];
    }

    #pragma unroll
    for (int off2 = 32; off2 > 0; off2 >>= 1) {
        accA += __shfl_down(accA, off2, 64);
        accR += __shfl_down(accR, off2, 64);
        accG += __shfl_down(accG, off2, 64);
        accB += __shfl_down(accB, off2, 64);
        accD += __shfl_down(accD, off2, 64);
    }
    if (lane == 0) {
        red[wave][0] = accA; red[wave][1] = accR; red[wave][2] = accG;
        red[wave][3] = accB; red[wave][4] = accD;
    }
    __syncthreads();
    if (tid == 0) {
        float A = 0.0f, R = 0.0f, G = 0.0f, Bv = 0.0f, D = 0.0f;
        #pragma unroll
        for (int w2 = 0; w2 < 4; ++w2) {
            A += red[w2][0]; R += red[w2][1]; G += red[w2][2];
            Bv += red[w2][3]; D += red[w2][4];
        }
        const float bg = 1.0f - A;
        out_rgb[ray*3+0] = R  + bg;
        out_rgb[ray*3+1] = G  + bg;
        out_rgb[ray*3+2] = Bv + bg;
        out_depth[ray] = D;
    }
}

extern "C" void kernel_launch(void* const* d_in, const int* in_sizes, int n_in,
                              void* d_out, int out_size, void* d_ws, size_t ws_size,
                              hipStream_t stream) {
    const float* rays_d = (const float*)d_in[0];
    const float* rays_o = (const float*)d_in[1];
    const float* grid   = (const float*)d_in[2];
    const int B = in_sizes[0] / 3;   // 4096

    float* out       = (float*)d_out;
    float* out_rgb   = out;
    float* out_alpha = out + (size_t)B*3;
    float* out_depth = out + (size_t)B*3 + (size_t)B*NT;

    int* perm = (int*)d_ws;

    prep_sort<<<1, 1024, 0, stream>>>(rays_d, rays_o, perm, B);
    nerf_grid_kernel<<<B, 256, 0, stream>>>(rays_d, rays_o, grid, perm,
                                            out_rgb, out_alpha, out_depth);
}